// Round 14
// baseline (350.395 us; speedup 1.0000x reference)
//
#include <hip/hip_runtime.h>
#include <hip/hip_bf16.h>

#define FDIM 256
#define EDIM 64
#define LEAKY 0.2f

// MFMA GEMM tiling
#define BM 128
#define BN 256
#define BK 32

#define SCAN_BLOCKS 64

typedef __attribute__((ext_vector_type(8))) short bfrag;   // 8 bf16 = 4 VGPR
typedef __attribute__((ext_vector_type(4))) float f4acc;   // 4 f32 accum

// fp32 -> bf16 bits, round-to-nearest-even
__device__ __forceinline__ unsigned f2bf(float x){
    unsigned u = __float_as_uint(x);
    return (u + 0x7FFFu + ((u >> 16) & 1u)) >> 16;
}
__device__ __forceinline__ float bf2f(unsigned b){
    return __uint_as_float(b << 16);
}
__device__ __forceinline__ unsigned pack_hi(float x, float y, float& hx, float& hy){
    unsigned bx = f2bf(x), by = f2bf(y);
    hx = bf2f(bx); hy = bf2f(by);
    return bx | (by << 16);
}
__device__ __forceinline__ unsigned pack_lo(float rx, float ry){
    return f2bf(rx) | (f2bf(ry) << 16);
}

// resident-grid barrier (grid <= #CUs so all blocks co-resident)
__device__ __forceinline__ void gbar(int* bar, int idx, int nb){
    __syncthreads();
    if (threadIdx.x == 0){
        __threadfence();
        atomicAdd(&bar[idx], 1);
        while (__hip_atomic_load(&bar[idx], __ATOMIC_ACQUIRE, __HIP_MEMORY_SCOPE_AGENT) < nb){}
        __threadfence();
    }
    __syncthreads();
}

// W conversion + dst histogram + flag zeroing, one pass
__global__ void k_prep(const float* __restrict__ W, unsigned short* __restrict__ W16,
                       const int* __restrict__ dst, int* __restrict__ counts,
                       int* __restrict__ bar, int E){
    int gt = blockIdx.x*256 + threadIdx.x;
    if (gt == 0){ bar[0] = 0; bar[1] = 0; }
    if (gt < (FDIM*FDIM)/4){
        int i = gt*4;
        float4 v = *(const float4*)&W[i];
        uint2 o;
        o.x = f2bf(v.x) | (f2bf(v.y) << 16);
        o.y = f2bf(v.z) | (f2bf(v.w) << 16);
        *(uint2*)&W16[i] = o;
    }
    if (gt < E) atomicAdd(&counts[dst[gt]], 1);
}

// z = h @ W^T via split-bf16 MFMA: A = hi+lo (in-kernel), B = bf16 pre-converted.
// Compact LDS (34 KB total) -> 4 blocks/CU for staging-latency hiding.
// smB: 4 slots/row, slot = (k8 ^ row ^ (row>>2)) & 3  (2-way-max bank pattern)
__global__ __launch_bounds__(256, 4) void k_gemm(const float* __restrict__ h,
                                                 const unsigned short* __restrict__ W16,
                                                 const float* __restrict__ A,
                                                 unsigned short* __restrict__ z16,
                                                 float* __restrict__ s_src,
                                                 float* __restrict__ s_dst, int M){
    __shared__ uint4 smA[BM*8];       // 16 KB: hi at k8^(row&7), lo at ^4
    __shared__ uint4 smB[BN*4];       // 16 KB: compact, swizzled
    __shared__ float sred[2][2][BM];  // 2 KB

    int tid = threadIdx.x;
    int m0 = blockIdx.x * BM;

    int wid  = tid >> 6;
    int lane = tid & 63;
    int wm = (wid >> 1) * 64;     // 0 / 64
    int wn = (wid & 1) * 128;     // 0 / 128
    int l15 = lane & 15;
    int l4  = lane >> 4;

    f4acc acc[4][8];
    #pragma unroll
    for (int i = 0; i < 4; ++i)
        #pragma unroll
        for (int j = 0; j < 8; ++j)
            acc[i][j] = (f4acc)(0.f);

    for (int kc = 0; kc < FDIM; kc += BK){
        // stage: A = 512 items (hi+lo conversion), B = 1024 items (copy)
        #pragma unroll
        for (int q = 0; q < 6; ++q){
            int p = tid + q*256;
            if (p < 512){
                int row = p >> 2, k8 = p & 3;
                int gr = m0 + row;
                float4 v0, v1;
                if (gr < M){
                    const float* g = &h[(size_t)gr*FDIM + kc + k8*8];
                    v0 = *(const float4*)g; v1 = *(const float4*)(g + 4);
                } else {
                    v0 = make_float4(0.f,0.f,0.f,0.f); v1 = v0;
                }
                uint4 hi, lo; float hx, hy;
                hi.x = pack_hi(v0.x, v0.y, hx, hy);
                lo.x = pack_lo(v0.x - hx, v0.y - hy);
                hi.y = pack_hi(v0.z, v0.w, hx, hy);
                lo.y = pack_lo(v0.z - hx, v0.w - hy);
                hi.z = pack_hi(v1.x, v1.y, hx, hy);
                lo.z = pack_lo(v1.x - hx, v1.y - hy);
                hi.w = pack_hi(v1.z, v1.w, hx, hy);
                lo.w = pack_lo(v1.z - hx, v1.w - hy);
                int sh = k8 ^ (row & 7);
                smA[row*8 + sh]       = hi;
                smA[row*8 + (sh ^ 4)] = lo;
            } else {
                int pb = p - 512;
                int row = pb >> 2, k8 = pb & 3;
                uint4 v = *(const uint4*)&W16[(size_t)row*FDIM + kc + k8*8];
                int sw = (k8 ^ row ^ (row >> 2)) & 3;
                smB[row*4 + sw] = v;
            }
        }
        __syncthreads();

        bfrag ah[4], al[4];
        #pragma unroll
        for (int mf = 0; mf < 4; ++mf){
            int row = wm + mf*16 + l15;
            int sh = l4 ^ (row & 7);
            ah[mf] = *(const bfrag*)&smA[row*8 + sh];
            al[mf] = *(const bfrag*)&smA[row*8 + (sh ^ 4)];
        }
        #pragma unroll
        for (int nf = 0; nf < 8; ++nf){
            int row = wn + nf*16 + l15;
            int sw = (l4 ^ row ^ (row >> 2)) & 3;
            bfrag bh = *(const bfrag*)&smB[row*4 + sw];
            #pragma unroll
            for (int mf = 0; mf < 4; ++mf){
                acc[mf][nf] = __builtin_amdgcn_mfma_f32_16x16x32_bf16(ah[mf], bh, acc[mf][nf], 0, 0, 0);
                acc[mf][nf] = __builtin_amdgcn_mfma_f32_16x16x32_bf16(al[mf], bh, acc[mf][nf], 0, 0, 0);
            }
        }
        __syncthreads();
    }

    // ---- z write (bf16) ----
    #pragma unroll
    for (int mf = 0; mf < 4; ++mf){
        #pragma unroll
        for (int nf = 0; nf < 8; ++nf){
            int gcol = wn + nf*16 + l15;
            #pragma unroll
            for (int r = 0; r < 4; ++r){
                int grow = m0 + wm + mf*16 + l4*4 + r;
                if (grow < M)
                    z16[(size_t)grow*FDIM + gcol] = (unsigned short)f2bf(acc[mf][nf][r]);
            }
        }
    }

    // ---- fused s_src / s_dst (complete per block, direct store) ----
    float aS[8], aD[8];
    #pragma unroll
    for (int nf = 0; nf < 8; ++nf){
        int gcol = wn + nf*16 + l15;
        aS[nf] = A[gcol];
        aD[nf] = A[FDIM + gcol];
    }
    #pragma unroll
    for (int mf = 0; mf < 4; ++mf){
        #pragma unroll
        for (int r = 0; r < 4; ++r){
            float ps = 0.f, pd = 0.f;
            #pragma unroll
            for (int nf = 0; nf < 8; ++nf){
                ps += acc[mf][nf][r] * aS[nf];
                pd += acc[mf][nf][r] * aD[nf];
            }
            #pragma unroll
            for (int o = 1; o < 16; o <<= 1){
                ps += __shfl_xor(ps, o);
                pd += __shfl_xor(pd, o);
            }
            if (l15 == 0){
                int row = wm + mf*16 + l4*4 + r;
                sred[wid & 1][0][row] = ps;
                sred[wid & 1][1][row] = pd;
            }
        }
    }
    __syncthreads();
    if (tid < BM){
        int grow = m0 + tid;
        if (grow < M){
            s_src[grow] = sred[0][0][tid] + sred[1][0][tid];
            s_dst[grow] = sred[0][1][tid] + sred[1][1][tid];
        }
    }
}

// fused 3-phase scan: counts -> exclusive offsets (+cursor copy), one launch
__global__ __launch_bounds__(256) void k_scan(int* __restrict__ counts, int* __restrict__ cursor,
                                              int* __restrict__ bsums, int* __restrict__ bar,
                                              int N, int E){
    __shared__ int sh[256];
    int tid = threadIdx.x;
    int chunk = (N + SCAN_BLOCKS - 1) / SCAN_BLOCKS;
    int c0 = blockIdx.x * chunk;
    int lim = min(c0 + chunk, N);

    int s = 0;
    for (int i = c0 + tid; i < lim; i += 256) s += counts[i];
    sh[tid] = s; __syncthreads();
    for (int o = 128; o > 0; o >>= 1){
        if (tid < o) sh[tid] += sh[tid + o];
        __syncthreads();
    }
    if (tid == 0) bsums[blockIdx.x] = sh[0];

    gbar(bar, 0, SCAN_BLOCKS);

    if (blockIdx.x == 0 && tid < 64){
        int v = bsums[tid];
        int orig = v;
        #pragma unroll
        for (int o = 1; o < 64; o <<= 1){
            int t = __shfl_up(v, o);
            if (tid >= o) v += t;
        }
        bsums[tid] = v - orig;
    }

    gbar(bar, 1, SCAN_BLOCKS);

    int base = c0 + tid*4;
    int v[4]; int ts = 0;
    #pragma unroll
    for (int l = 0; l < 4; l++){
        int idx = base + l;
        v[l] = (idx < lim) ? counts[idx] : 0;
        ts += v[l];
    }
    __syncthreads();
    sh[tid] = ts; __syncthreads();
    int acc = ts;
    for (int o = 1; o < 256; o <<= 1){
        int t = (tid >= o) ? sh[tid - o] : 0;
        __syncthreads();
        acc += t; sh[tid] = acc;
        __syncthreads();
    }
    int excl = acc - ts + bsums[blockIdx.x];
    #pragma unroll
    for (int l = 0; l < 4; l++){
        int idx = base + l;
        if (idx < lim){ counts[idx] = excl; cursor[idx] = excl; }
        excl += v[l];
    }
    if (blockIdx.x == 0 && tid == 0) counts[N] = E;
}

// per-edge: e_feat dot + logit + leaky-relu + counting-sort write {src, logit}
__global__ void k_edge(const float* __restrict__ ef, const float* __restrict__ A,
                       const float* __restrict__ s_src, const float* __restrict__ s_dst,
                       const int* __restrict__ src, const int* __restrict__ dst,
                       int* __restrict__ cursor, int2* __restrict__ epair, int E){
    int gt = blockIdx.x*256 + threadIdx.x;
    int e = gt >> 4, l4 = gt & 15;
    if (e >= E) return;
    float4 f  = *(const float4*)&ef[(size_t)e*EDIM + l4*4];
    float4 ae = *(const float4*)&A[2*FDIM + l4*4];
    float v = f.x*ae.x + f.y*ae.y + f.z*ae.z + f.w*ae.w;
    v += __shfl_xor(v, 8); v += __shfl_xor(v, 4);
    v += __shfl_xor(v, 2); v += __shfl_xor(v, 1);
    if (l4 == 0){
        int d = dst[e];
        float lg = v + s_src[src[e]] + s_dst[d];
        lg = lg > 0.f ? lg : LEAKY*lg;
        int p = atomicAdd(&cursor[d], 1);
        int2 pr; pr.x = src[e]; pr.y = __float_as_int(lg);
        epair[p] = pr;
    }
}

// final: 4 dst nodes per block, one wave per node; coalesced epair + shfl
__global__ __launch_bounds__(256) void k_out(const unsigned short* __restrict__ z16,
                                             const int* __restrict__ offsets,
                                             const int2* __restrict__ epair,
                                             float* __restrict__ out, int N){
    int n = blockIdx.x*4 + (threadIdx.x >> 6);
    int lane = threadIdx.x & 63;
    if (n >= N) return;
    int i0 = offsets[n], i1 = offsets[n+1];

    float mlane = -3.402823466e38f;
    for (int i = i0 + lane; i < i1; i += 64)
        mlane = fmaxf(mlane, __int_as_float(epair[i].y));
    float mx = mlane;
    #pragma unroll
    for (int o = 32; o > 0; o >>= 1)
        mx = fmaxf(mx, __shfl_xor(mx, o));

    float4 a[4];
    a[0] = make_float4(0,0,0,0); a[1] = a[0]; a[2] = a[0]; a[3] = a[0];
    float dw = 0.f;
    const unsigned short* zb = z16 + lane*4;

    for (int base = i0; base < i1; base += 64){
        int cnt = min(64, i1 - base);
        int2 pe = make_int2(0, 0);
        float w = 0.f;
        if (lane < cnt){
            pe = epair[base + lane];
            w = __expf(__int_as_float(pe.y) - mx);
        }
        dw += w;
        int j = 0;
        for (; j + 7 < cnt; j += 8){
            float wj[8]; int sj[8]; uint2 rj[8];
            #pragma unroll
            for (int q = 0; q < 8; ++q){
                wj[q] = __shfl(w, j + q);
                sj[q] = __shfl(pe.x, j + q);
            }
            #pragma unroll
            for (int q = 0; q < 8; ++q)
                rj[q] = *(const uint2*)&zb[(size_t)sj[q]*FDIM];
            #pragma unroll
            for (int q = 0; q < 8; ++q){
                a[q & 3].x += wj[q]*bf2f(rj[q].x & 0xffffu);
                a[q & 3].y += wj[q]*bf2f(rj[q].x >> 16);
                a[q & 3].z += wj[q]*bf2f(rj[q].y & 0xffffu);
                a[q & 3].w += wj[q]*bf2f(rj[q].y >> 16);
            }
        }
        for (; j < cnt; ++j){
            float wq = __shfl(w, j);
            int   sq = __shfl(pe.x, j);
            uint2 r0 = *(const uint2*)&zb[(size_t)sq*FDIM];
            a[0].x += wq*bf2f(r0.x & 0xffffu);
            a[0].y += wq*bf2f(r0.x >> 16);
            a[0].z += wq*bf2f(r0.y & 0xffffu);
            a[0].w += wq*bf2f(r0.y >> 16);
        }
    }

    #pragma unroll
    for (int o = 32; o > 0; o >>= 1)
        dw += __shfl_xor(dw, o);

    float inv = (i1 > i0) ? 1.f / dw : 0.f;
    float4 res;
    res.x = ((a[0].x + a[1].x) + (a[2].x + a[3].x)) * inv;
    res.y = ((a[0].y + a[1].y) + (a[2].y + a[3].y)) * inv;
    res.z = ((a[0].z + a[1].z) + (a[2].z + a[3].z)) * inv;
    res.w = ((a[0].w + a[1].w) + (a[2].w + a[3].w)) * inv;
    *(float4*)&out[(size_t)n*FDIM + lane*4] = res;
}

extern "C" void kernel_launch(void* const* d_in, const int* in_sizes, int n_in,
                              void* d_out, int out_size, void* d_ws, size_t ws_size,
                              hipStream_t stream){
    const float* h  = (const float*)d_in[0];
    const float* ef = (const float*)d_in[1];
    const float* W  = (const float*)d_in[2];
    const float* A  = (const float*)d_in[3];
    const int*  src = (const int*)d_in[4];
    const int*  dst = (const int*)d_in[5];
    float* out = (float*)d_out;
    int N = in_sizes[0] / FDIM;
    int E = in_sizes[4];

    char* ws = (char*)d_ws;
    size_t off = 0;
    auto alloc = [&](size_t nbytes)->char*{
        char* p = ws + off;
        off = (off + nbytes + 255) & ~(size_t)255;
        return p;
    };
    unsigned short* z16 = (unsigned short*)alloc((size_t)N*FDIM*2);
    unsigned short* W16 = (unsigned short*)alloc((size_t)FDIM*FDIM*2);
    float* s_src  = (float*)alloc((size_t)N*4);
    float* s_dst  = (float*)alloc((size_t)N*4);
    int*   counts = (int*)alloc((size_t)(N+1)*4);
    int*   cursor = (int*)alloc((size_t)N*4);
    int2*  epair  = (int2*)alloc((size_t)E*8);
    int*   bsums  = (int*)alloc(SCAN_BLOCKS*4);
    int*   bar    = (int*)alloc(2*4);

    hipMemsetAsync(counts, 0, (size_t)(N+1)*4, stream);
    hipLaunchKernelGGL(k_prep, dim3((E+255)/256), dim3(256), 0, stream,
                       W, W16, dst, counts, bar, E);
    hipLaunchKernelGGL(k_gemm, dim3((N+BM-1)/BM), dim3(256), 0, stream,
                       h, W16, A, z16, s_src, s_dst, N);
    hipLaunchKernelGGL(k_scan, dim3(SCAN_BLOCKS), dim3(256), 0, stream,
                       counts, cursor, bsums, bar, N, E);
    hipLaunchKernelGGL(k_edge, dim3((E+15)/16), dim3(256), 0, stream,
                       ef, A, s_src, s_dst, src, dst, cursor, epair, E);
    hipLaunchKernelGGL(k_out, dim3((N+3)/4), dim3(256), 0, stream,
                       z16, counts, epair, out, N);
}

// Round 15
// 237.834 us; speedup vs baseline: 1.4733x; 1.4733x over previous
//
#include <hip/hip_runtime.h>
#include <hip/hip_bf16.h>

#define FDIM 256
#define EDIM 64
#define LEAKY 0.2f

// MFMA GEMM tiling: 512 threads, 8 waves of 64x64
#define BM 128
#define BN 256
#define BK 32

#define SCAN_BLOCKS 64

typedef __attribute__((ext_vector_type(8))) short bfrag;   // 8 bf16 = 4 VGPR
typedef __attribute__((ext_vector_type(4))) float f4acc;   // 4 f32 accum

// fp32 -> bf16 bits, round-to-nearest-even
__device__ __forceinline__ unsigned f2bf(float x){
    unsigned u = __float_as_uint(x);
    return (u + 0x7FFFu + ((u >> 16) & 1u)) >> 16;
}
__device__ __forceinline__ float bf2f(unsigned b){
    return __uint_as_float(b << 16);
}
__device__ __forceinline__ unsigned pack_hi(float x, float y, float& hx, float& hy){
    unsigned bx = f2bf(x), by = f2bf(y);
    hx = bf2f(bx); hy = bf2f(by);
    return bx | (by << 16);
}
__device__ __forceinline__ unsigned pack_lo(float rx, float ry){
    return f2bf(rx) | (f2bf(ry) << 16);
}

// resident-grid barrier (grid <= #CUs so all blocks co-resident)
__device__ __forceinline__ void gbar(int* bar, int idx, int nb){
    __syncthreads();
    if (threadIdx.x == 0){
        __threadfence();
        atomicAdd(&bar[idx], 1);
        while (__hip_atomic_load(&bar[idx], __ATOMIC_ACQUIRE, __HIP_MEMORY_SCOPE_AGENT) < nb){}
        __threadfence();
    }
    __syncthreads();
}

// W conversion + dst histogram + flag zeroing, one pass
__global__ void k_prep(const float* __restrict__ W, unsigned short* __restrict__ W16,
                       const int* __restrict__ dst, int* __restrict__ counts,
                       int* __restrict__ bar, int E){
    int gt = blockIdx.x*256 + threadIdx.x;
    if (gt == 0){ bar[0] = 0; bar[1] = 0; }
    if (gt < (FDIM*FDIM)/4){
        int i = gt*4;
        float4 v = *(const float4*)&W[i];
        uint2 o;
        o.x = f2bf(v.x) | (f2bf(v.y) << 16);
        o.y = f2bf(v.z) | (f2bf(v.w) << 16);
        *(uint2*)&W16[i] = o;
    }
    if (gt < E) atomicAdd(&counts[dst[gt]], 1);
}

// z = h @ W^T via split-bf16 MFMA: A = hi+lo (in-kernel), B = bf16 pre-converted.
// 512 threads / 8 waves, per-wave 64x64 tile -> acc[4][4] (64 VGPR), fits the
// 128-VGPR cap of (512,4) = 2 blocks/CU = 4 waves/SIMD (2x r8's latency hiding).
__global__ __launch_bounds__(512, 4) void k_gemm(const float* __restrict__ h,
                                                 const unsigned short* __restrict__ W16,
                                                 const float* __restrict__ A,
                                                 unsigned short* __restrict__ z16,
                                                 float* __restrict__ s_src,
                                                 float* __restrict__ s_dst, int M){
    __shared__ uint4 smA[BM*8];       // 16 KB: hi at k8^(row&7), lo at ^4
    __shared__ uint4 smB[BN*4];       // 16 KB: compact, slot (k8^row^(row>>2))&3
    __shared__ float sred[4][2][BM];  // 4 KB: per-wn-group partials

    int tid = threadIdx.x;
    int m0 = blockIdx.x * BM;

    int wid  = tid >> 6;          // 0..7
    int lane = tid & 63;
    int wm = (wid >> 2) * 64;     // 0 / 64
    int wn = (wid & 3) * 64;      // 0 / 64 / 128 / 192
    int l15 = lane & 15;
    int l4  = lane >> 4;

    f4acc acc[4][4];
    #pragma unroll
    for (int i = 0; i < 4; ++i)
        #pragma unroll
        for (int j = 0; j < 4; ++j)
            acc[i][j] = (f4acc)(0.f);

    for (int kc = 0; kc < FDIM; kc += BK){
        // ---- A staging: 512 items, 1/thread, fp32 -> hi/lo bf16
        {
            int row = tid >> 2, k8 = tid & 3;
            int gr = m0 + row;
            float4 v0, v1;
            if (gr < M){
                const float* g = &h[(size_t)gr*FDIM + kc + k8*8];
                v0 = *(const float4*)g; v1 = *(const float4*)(g + 4);
            } else {
                v0 = make_float4(0.f,0.f,0.f,0.f); v1 = v0;
            }
            uint4 hi, lo; float hx, hy;
            hi.x = pack_hi(v0.x, v0.y, hx, hy);
            lo.x = pack_lo(v0.x - hx, v0.y - hy);
            hi.y = pack_hi(v0.z, v0.w, hx, hy);
            lo.y = pack_lo(v0.z - hx, v0.w - hy);
            hi.z = pack_hi(v1.x, v1.y, hx, hy);
            lo.z = pack_lo(v1.x - hx, v1.y - hy);
            hi.w = pack_hi(v1.z, v1.w, hx, hy);
            lo.w = pack_lo(v1.z - hx, v1.w - hy);
            int sh = k8 ^ (row & 7);
            smA[row*8 + sh]       = hi;
            smA[row*8 + (sh ^ 4)] = lo;
        }
        // ---- B staging: 1024 items, 2/thread, pure copy
        #pragma unroll
        for (int q = 0; q < 2; ++q){
            int p = tid + q*512;
            int row = p >> 2, k8 = p & 3;
            uint4 v = *(const uint4*)&W16[(size_t)row*FDIM + kc + k8*8];
            int sw = (k8 ^ row ^ (row >> 2)) & 3;
            smB[row*4 + sw] = v;
        }
        __syncthreads();

        // preload 4 B frags, then stream A frags per mf (keeps VGPR low)
        bfrag bhv[4];
        #pragma unroll
        for (int nf = 0; nf < 4; ++nf){
            int row = wn + nf*16 + l15;
            int sw = (l4 ^ row ^ (row >> 2)) & 3;
            bhv[nf] = *(const bfrag*)&smB[row*4 + sw];
        }
        #pragma unroll
        for (int mf = 0; mf < 4; ++mf){
            int row = wm + mf*16 + l15;
            int sh = l4 ^ (row & 7);
            bfrag ah = *(const bfrag*)&smA[row*8 + sh];
            bfrag al = *(const bfrag*)&smA[row*8 + (sh ^ 4)];
            #pragma unroll
            for (int nf = 0; nf < 4; ++nf){
                acc[mf][nf] = __builtin_amdgcn_mfma_f32_16x16x32_bf16(ah, bhv[nf], acc[mf][nf], 0, 0, 0);
                acc[mf][nf] = __builtin_amdgcn_mfma_f32_16x16x32_bf16(al, bhv[nf], acc[mf][nf], 0, 0, 0);
            }
        }
        __syncthreads();
    }

    // ---- z write (bf16): col = wn + nf*16 + l15, row = wm + mf*16 + l4*4 + r
    #pragma unroll
    for (int mf = 0; mf < 4; ++mf){
        #pragma unroll
        for (int nf = 0; nf < 4; ++nf){
            int gcol = wn + nf*16 + l15;
            #pragma unroll
            for (int r = 0; r < 4; ++r){
                int grow = m0 + wm + mf*16 + l4*4 + r;
                if (grow < M)
                    z16[(size_t)grow*FDIM + gcol] = (unsigned short)f2bf(acc[mf][nf][r]);
            }
        }
    }

    // ---- fused s_src / s_dst ----
    float aS[4], aD[4];
    #pragma unroll
    for (int nf = 0; nf < 4; ++nf){
        int gcol = wn + nf*16 + l15;
        aS[nf] = A[gcol];
        aD[nf] = A[FDIM + gcol];
    }
    #pragma unroll
    for (int mf = 0; mf < 4; ++mf){
        #pragma unroll
        for (int r = 0; r < 4; ++r){
            float ps = 0.f, pd = 0.f;
            #pragma unroll
            for (int nf = 0; nf < 4; ++nf){
                ps += acc[mf][nf][r] * aS[nf];
                pd += acc[mf][nf][r] * aD[nf];
            }
            #pragma unroll
            for (int o = 1; o < 16; o <<= 1){
                ps += __shfl_xor(ps, o);
                pd += __shfl_xor(pd, o);
            }
            if (l15 == 0){
                int row = wm + mf*16 + l4*4 + r;
                sred[wid & 3][0][row] = ps;
                sred[wid & 3][1][row] = pd;
            }
        }
    }
    __syncthreads();
    if (tid < BM){
        int grow = m0 + tid;
        if (grow < M){
            s_src[grow] = (sred[0][0][tid] + sred[1][0][tid]) + (sred[2][0][tid] + sred[3][0][tid]);
            s_dst[grow] = (sred[0][1][tid] + sred[1][1][tid]) + (sred[2][1][tid] + sred[3][1][tid]);
        }
    }
}

// fused 3-phase scan: counts -> exclusive offsets (+cursor copy), one launch
__global__ __launch_bounds__(256) void k_scan(int* __restrict__ counts, int* __restrict__ cursor,
                                              int* __restrict__ bsums, int* __restrict__ bar,
                                              int N, int E){
    __shared__ int sh[256];
    int tid = threadIdx.x;
    int chunk = (N + SCAN_BLOCKS - 1) / SCAN_BLOCKS;
    int c0 = blockIdx.x * chunk;
    int lim = min(c0 + chunk, N);

    int s = 0;
    for (int i = c0 + tid; i < lim; i += 256) s += counts[i];
    sh[tid] = s; __syncthreads();
    for (int o = 128; o > 0; o >>= 1){
        if (tid < o) sh[tid] += sh[tid + o];
        __syncthreads();
    }
    if (tid == 0) bsums[blockIdx.x] = sh[0];

    gbar(bar, 0, SCAN_BLOCKS);

    if (blockIdx.x == 0 && tid < 64){
        int v = bsums[tid];
        int orig = v;
        #pragma unroll
        for (int o = 1; o < 64; o <<= 1){
            int t = __shfl_up(v, o);
            if (tid >= o) v += t;
        }
        bsums[tid] = v - orig;
    }

    gbar(bar, 1, SCAN_BLOCKS);

    int base = c0 + tid*4;
    int v[4]; int ts = 0;
    #pragma unroll
    for (int l = 0; l < 4; l++){
        int idx = base + l;
        v[l] = (idx < lim) ? counts[idx] : 0;
        ts += v[l];
    }
    __syncthreads();
    sh[tid] = ts; __syncthreads();
    int acc = ts;
    for (int o = 1; o < 256; o <<= 1){
        int t = (tid >= o) ? sh[tid - o] : 0;
        __syncthreads();
        acc += t; sh[tid] = acc;
        __syncthreads();
    }
    int excl = acc - ts + bsums[blockIdx.x];
    #pragma unroll
    for (int l = 0; l < 4; l++){
        int idx = base + l;
        if (idx < lim){ counts[idx] = excl; cursor[idx] = excl; }
        excl += v[l];
    }
    if (blockIdx.x == 0 && tid == 0) counts[N] = E;
}

// per-edge: e_feat dot + logit + leaky-relu + counting-sort write {src, logit}
__global__ void k_edge(const float* __restrict__ ef, const float* __restrict__ A,
                       const float* __restrict__ s_src, const float* __restrict__ s_dst,
                       const int* __restrict__ src, const int* __restrict__ dst,
                       int* __restrict__ cursor, int2* __restrict__ epair, int E){
    int gt = blockIdx.x*256 + threadIdx.x;
    int e = gt >> 4, l4 = gt & 15;
    if (e >= E) return;
    float4 f  = *(const float4*)&ef[(size_t)e*EDIM + l4*4];
    float4 ae = *(const float4*)&A[2*FDIM + l4*4];
    float v = f.x*ae.x + f.y*ae.y + f.z*ae.z + f.w*ae.w;
    v += __shfl_xor(v, 8); v += __shfl_xor(v, 4);
    v += __shfl_xor(v, 2); v += __shfl_xor(v, 1);
    if (l4 == 0){
        int d = dst[e];
        float lg = v + s_src[src[e]] + s_dst[d];
        lg = lg > 0.f ? lg : LEAKY*lg;
        int p = atomicAdd(&cursor[d], 1);
        int2 pr; pr.x = src[e]; pr.y = __float_as_int(lg);
        epair[p] = pr;
    }
}

// final: 4 dst nodes per block, one wave per node; coalesced epair + shfl
__global__ __launch_bounds__(256) void k_out(const unsigned short* __restrict__ z16,
                                             const int* __restrict__ offsets,
                                             const int2* __restrict__ epair,
                                             float* __restrict__ out, int N){
    int n = blockIdx.x*4 + (threadIdx.x >> 6);
    int lane = threadIdx.x & 63;
    if (n >= N) return;
    int i0 = offsets[n], i1 = offsets[n+1];

    float mlane = -3.402823466e38f;
    for (int i = i0 + lane; i < i1; i += 64)
        mlane = fmaxf(mlane, __int_as_float(epair[i].y));
    float mx = mlane;
    #pragma unroll
    for (int o = 32; o > 0; o >>= 1)
        mx = fmaxf(mx, __shfl_xor(mx, o));

    float4 a[4];
    a[0] = make_float4(0,0,0,0); a[1] = a[0]; a[2] = a[0]; a[3] = a[0];
    float dw = 0.f;
    const unsigned short* zb = z16 + lane*4;

    for (int base = i0; base < i1; base += 64){
        int cnt = min(64, i1 - base);
        int2 pe = make_int2(0, 0);
        float w = 0.f;
        if (lane < cnt){
            pe = epair[base + lane];
            w = __expf(__int_as_float(pe.y) - mx);
        }
        dw += w;
        int j = 0;
        for (; j + 7 < cnt; j += 8){
            float wj[8]; int sj[8]; uint2 rj[8];
            #pragma unroll
            for (int q = 0; q < 8; ++q){
                wj[q] = __shfl(w, j + q);
                sj[q] = __shfl(pe.x, j + q);
            }
            #pragma unroll
            for (int q = 0; q < 8; ++q)
                rj[q] = *(const uint2*)&zb[(size_t)sj[q]*FDIM];
            #pragma unroll
            for (int q = 0; q < 8; ++q){
                a[q & 3].x += wj[q]*bf2f(rj[q].x & 0xffffu);
                a[q & 3].y += wj[q]*bf2f(rj[q].x >> 16);
                a[q & 3].z += wj[q]*bf2f(rj[q].y & 0xffffu);
                a[q & 3].w += wj[q]*bf2f(rj[q].y >> 16);
            }
        }
        for (; j < cnt; ++j){
            float wq = __shfl(w, j);
            int   sq = __shfl(pe.x, j);
            uint2 r0 = *(const uint2*)&zb[(size_t)sq*FDIM];
            a[0].x += wq*bf2f(r0.x & 0xffffu);
            a[0].y += wq*bf2f(r0.x >> 16);
            a[0].z += wq*bf2f(r0.y & 0xffffu);
            a[0].w += wq*bf2f(r0.y >> 16);
        }
    }

    #pragma unroll
    for (int o = 32; o > 0; o >>= 1)
        dw += __shfl_xor(dw, o);

    float inv = (i1 > i0) ? 1.f / dw : 0.f;
    float4 res;
    res.x = ((a[0].x + a[1].x) + (a[2].x + a[3].x)) * inv;
    res.y = ((a[0].y + a[1].y) + (a[2].y + a[3].y)) * inv;
    res.z = ((a[0].z + a[1].z) + (a[2].z + a[3].z)) * inv;
    res.w = ((a[0].w + a[1].w) + (a[2].w + a[3].w)) * inv;
    *(float4*)&out[(size_t)n*FDIM + lane*4] = res;
}

extern "C" void kernel_launch(void* const* d_in, const int* in_sizes, int n_in,
                              void* d_out, int out_size, void* d_ws, size_t ws_size,
                              hipStream_t stream){
    const float* h  = (const float*)d_in[0];
    const float* ef = (const float*)d_in[1];
    const float* W  = (const float*)d_in[2];
    const float* A  = (const float*)d_in[3];
    const int*  src = (const int*)d_in[4];
    const int*  dst = (const int*)d_in[5];
    float* out = (float*)d_out;
    int N = in_sizes[0] / FDIM;
    int E = in_sizes[4];

    char* ws = (char*)d_ws;
    size_t off = 0;
    auto alloc = [&](size_t nbytes)->char*{
        char* p = ws + off;
        off = (off + nbytes + 255) & ~(size_t)255;
        return p;
    };
    unsigned short* z16 = (unsigned short*)alloc((size_t)N*FDIM*2);
    unsigned short* W16 = (unsigned short*)alloc((size_t)FDIM*FDIM*2);
    float* s_src  = (float*)alloc((size_t)N*4);
    float* s_dst  = (float*)alloc((size_t)N*4);
    int*   counts = (int*)alloc((size_t)(N+1)*4);
    int*   cursor = (int*)alloc((size_t)N*4);
    int2*  epair  = (int2*)alloc((size_t)E*8);
    int*   bsums  = (int*)alloc(SCAN_BLOCKS*4);
    int*   bar    = (int*)alloc(2*4);

    hipMemsetAsync(counts, 0, (size_t)(N+1)*4, stream);
    hipLaunchKernelGGL(k_prep, dim3((E+255)/256), dim3(256), 0, stream,
                       W, W16, dst, counts, bar, E);
    hipLaunchKernelGGL(k_gemm, dim3((N+BM-1)/BM), dim3(512), 0, stream,
                       h, W16, A, z16, s_src, s_dst, N);
    hipLaunchKernelGGL(k_scan, dim3(SCAN_BLOCKS), dim3(256), 0, stream,
                       counts, cursor, bsums, bar, N, E);
    hipLaunchKernelGGL(k_edge, dim3((E+15)/16), dim3(256), 0, stream,
                       ef, A, s_src, s_dst, src, dst, cursor, epair, E);
    hipLaunchKernelGGL(k_out, dim3((N+3)/4), dim3(256), 0, stream,
                       z16, counts, epair, out, N);
}

// Round 16
// 230.018 us; speedup vs baseline: 1.5233x; 1.0340x over previous
//
#include <hip/hip_runtime.h>
#include <hip/hip_bf16.h>

#define FDIM 256
#define EDIM 64
#define LEAKY 0.2f

// MFMA GEMM tiling: full-width column block
#define BM 128
#define BN 256
#define BK 32

typedef __attribute__((ext_vector_type(8))) short bfrag;   // 8 bf16 = 4 VGPR
typedef __attribute__((ext_vector_type(4))) float f4acc;   // 4 f32 accum

// fp32 -> bf16 bits, round-to-nearest-even
__device__ __forceinline__ unsigned f2bf(float x){
    unsigned u = __float_as_uint(x);
    return (u + 0x7FFFu + ((u >> 16) & 1u)) >> 16;
}
__device__ __forceinline__ float bf2f(unsigned b){
    return __uint_as_float(b << 16);
}
__device__ __forceinline__ unsigned pack_hi(float x, float y, float& hx, float& hy){
    unsigned bx = f2bf(x), by = f2bf(y);
    hx = bf2f(bx); hy = bf2f(by);
    return bx | (by << 16);
}
__device__ __forceinline__ unsigned pack_lo(float rx, float ry){
    return f2bf(rx) | (f2bf(ry) << 16);
}

// W (fp32 256x256) -> bf16 once
__global__ void k_wconv(const float* __restrict__ W, unsigned short* __restrict__ W16){
    int i = (blockIdx.x*256 + threadIdx.x) * 4;   // 16384 threads x 4 elems
    float4 v = *(const float4*)&W[i];
    uint2 o;
    o.x = f2bf(v.x) | (f2bf(v.y) << 16);
    o.y = f2bf(v.z) | (f2bf(v.w) << 16);
    *(uint2*)&W16[i] = o;
}

// z = h @ W^T via split-bf16 MFMA: A = hi+lo (converted here), B = bf16 (pre-converted).
// acc += Ah*Bh + Al*Bh. Output bf16 z16 + complete s_src/s_dst per row (direct store).
__global__ __launch_bounds__(256, 2) void k_gemm(const float* __restrict__ h,
                                                 const unsigned short* __restrict__ W16,
                                                 const float* __restrict__ A,
                                                 unsigned short* __restrict__ z16,
                                                 float* __restrict__ s_src,
                                                 float* __restrict__ s_dst, int M){
    __shared__ uint4 smA[BM*8];       // 16 KB: hi at slot k8^(row&7), lo at ^4
    __shared__ uint4 smB[BN*8];       // 32 KB: hi at slot k8^(row&7)
    __shared__ float sred[2][2][BM];  // [wn-half][src/dst][row]

    int tid = threadIdx.x;
    int m0 = blockIdx.x * BM;

    int wid  = tid >> 6;
    int lane = tid & 63;
    int wm = (wid >> 1) * 64;     // 0 / 64
    int wn = (wid & 1) * 128;     // 0 / 128
    int l15 = lane & 15;
    int l4  = lane >> 4;

    f4acc acc[4][8];
    #pragma unroll
    for (int i = 0; i < 4; ++i)
        #pragma unroll
        for (int j = 0; j < 8; ++j)
            acc[i][j] = (f4acc)(0.f);

    for (int kc = 0; kc < FDIM; kc += BK){
        // stage: A = 512 items (hi+lo conversion), B = 1024 items (copy)
        #pragma unroll
        for (int q = 0; q < 6; ++q){
            int p = tid + q*256;
            if (p < 512){
                int row = p >> 2, k8 = p & 3;
                int gr = m0 + row;
                float4 v0, v1;
                if (gr < M){
                    const float* g = &h[(size_t)gr*FDIM + kc + k8*8];
                    v0 = *(const float4*)g; v1 = *(const float4*)(g + 4);
                } else {
                    v0 = make_float4(0.f,0.f,0.f,0.f); v1 = v0;
                }
                uint4 hi, lo; float hx, hy;
                hi.x = pack_hi(v0.x, v0.y, hx, hy);
                lo.x = pack_lo(v0.x - hx, v0.y - hy);
                hi.y = pack_hi(v0.z, v0.w, hx, hy);
                lo.y = pack_lo(v0.z - hx, v0.w - hy);
                hi.z = pack_hi(v1.x, v1.y, hx, hy);
                lo.z = pack_lo(v1.x - hx, v1.y - hy);
                hi.w = pack_hi(v1.z, v1.w, hx, hy);
                lo.w = pack_lo(v1.z - hx, v1.w - hy);
                int sh = k8 ^ (row & 7);
                smA[row*8 + sh]       = hi;
                smA[row*8 + (sh ^ 4)] = lo;
            } else {
                int pb = p - 512;
                int row = pb >> 2, k8 = pb & 3;   // row 0..255 = output col
                uint4 v = *(const uint4*)&W16[(size_t)row*FDIM + kc + k8*8];
                smB[row*8 + (k8 ^ (row & 7))] = v;
            }
        }
        __syncthreads();

        bfrag ah[4], al[4];
        #pragma unroll
        for (int mf = 0; mf < 4; ++mf){
            int row = wm + mf*16 + l15;
            int sh = l4 ^ (row & 7);
            ah[mf] = *(const bfrag*)&smA[row*8 + sh];
            al[mf] = *(const bfrag*)&smA[row*8 + (sh ^ 4)];
        }
        #pragma unroll
        for (int nf = 0; nf < 8; ++nf){
            int row = wn + nf*16 + l15;
            bfrag bh = *(const bfrag*)&smB[row*8 + (l4 ^ (row & 7))];
            #pragma unroll
            for (int mf = 0; mf < 4; ++mf){
                acc[mf][nf] = __builtin_amdgcn_mfma_f32_16x16x32_bf16(ah[mf], bh, acc[mf][nf], 0, 0, 0);
                acc[mf][nf] = __builtin_amdgcn_mfma_f32_16x16x32_bf16(al[mf], bh, acc[mf][nf], 0, 0, 0);
            }
        }
        __syncthreads();
    }

    // ---- z write (bf16): col = wn + nf*16 + l15, row = wm + mf*16 + l4*4 + r
    #pragma unroll
    for (int mf = 0; mf < 4; ++mf){
        #pragma unroll
        for (int nf = 0; nf < 8; ++nf){
            int gcol = wn + nf*16 + l15;
            #pragma unroll
            for (int r = 0; r < 4; ++r){
                int grow = m0 + wm + mf*16 + l4*4 + r;
                if (grow < M)
                    z16[(size_t)grow*FDIM + gcol] = (unsigned short)f2bf(acc[mf][nf][r]);
            }
        }
    }

    // ---- fused s_src / s_dst (complete per block, direct store) ----
    float aS[8], aD[8];
    #pragma unroll
    for (int nf = 0; nf < 8; ++nf){
        int gcol = wn + nf*16 + l15;
        aS[nf] = A[gcol];
        aD[nf] = A[FDIM + gcol];
    }
    #pragma unroll
    for (int mf = 0; mf < 4; ++mf){
        #pragma unroll
        for (int r = 0; r < 4; ++r){
            float ps = 0.f, pd = 0.f;
            #pragma unroll
            for (int nf = 0; nf < 8; ++nf){
                ps += acc[mf][nf][r] * aS[nf];
                pd += acc[mf][nf][r] * aD[nf];
            }
            #pragma unroll
            for (int o = 1; o < 16; o <<= 1){
                ps += __shfl_xor(ps, o);
                pd += __shfl_xor(pd, o);
            }
            if (l15 == 0){
                int row = wm + mf*16 + l4*4 + r;
                sred[wid & 1][0][row] = ps;
                sred[wid & 1][1][row] = pd;
            }
        }
    }
    __syncthreads();
    if (tid < BM){
        int grow = m0 + tid;
        if (grow < M){
            s_src[grow] = sred[0][0][tid] + sred[1][0][tid];
            s_dst[grow] = sred[0][1][tid] + sred[1][1][tid];
        }
    }
}

// degree histogram
__global__ void k_count(const int* __restrict__ dst, int* __restrict__ counts, int E){
    int e = blockIdx.x*256 + threadIdx.x;
    if (e < E) atomicAdd(&counts[dst[e]], 1);
}

// scan phase 1: per-1024-chunk sums
__global__ void k_chunk_sums(const int* __restrict__ counts, int* __restrict__ bsums, int N){
    __shared__ int sh[256];
    int base = blockIdx.x*1024;
    int s = 0;
    for (int i = threadIdx.x; i < 1024; i += 256){
        int idx = base + i;
        s += (idx < N) ? counts[idx] : 0;
    }
    sh[threadIdx.x] = s; __syncthreads();
    for (int o = 128; o > 0; o >>= 1){
        if (threadIdx.x < o) sh[threadIdx.x] += sh[threadIdx.x + o];
        __syncthreads();
    }
    if (threadIdx.x == 0) bsums[blockIdx.x] = sh[0];
}

// scan phase 2: exclusive scan of chunk sums (nb <= 1024), single block
__global__ void k_scan_small(int* __restrict__ b, int nb){
    __shared__ int sh[1024];
    int tid = threadIdx.x;
    int v = (tid < nb) ? b[tid] : 0;
    sh[tid] = v; __syncthreads();
    int acc = v;
    for (int o = 1; o < 1024; o <<= 1){
        int t = (tid >= o) ? sh[tid - o] : 0;
        __syncthreads();
        acc += t; sh[tid] = acc;
        __syncthreads();
    }
    if (tid < nb) b[tid] = acc - v;
}

// scan phase 3: per-chunk exclusive scan -> offsets (in place) + cursor copy
__global__ void k_scan_chunks(int* __restrict__ counts, int* __restrict__ cursor,
                              const int* __restrict__ bsums, int N, int E){
    __shared__ int sh[256];
    int tid = threadIdx.x;
    int base = blockIdx.x*1024 + tid*4;
    int v[4]; int s = 0;
    #pragma unroll
    for (int l = 0; l < 4; l++){
        int idx = base + l;
        v[l] = (idx < N) ? counts[idx] : 0;
        s += v[l];
    }
    sh[tid] = s; __syncthreads();
    int acc = s;
    for (int o = 1; o < 256; o <<= 1){
        int t = (tid >= o) ? sh[tid - o] : 0;
        __syncthreads();
        acc += t; sh[tid] = acc;
        __syncthreads();
    }
    int excl = acc - s + bsums[blockIdx.x];
    #pragma unroll
    for (int l = 0; l < 4; l++){
        int idx = base + l;
        if (idx < N){ counts[idx] = excl; cursor[idx] = excl; }
        excl += v[l];
    }
    if (blockIdx.x == 0 && tid == 0) counts[N] = E;
}

// per-edge: e_feat dot + logit + leaky-relu + counting-sort write {src, logit}
__global__ void k_edge(const float* __restrict__ ef, const float* __restrict__ A,
                       const float* __restrict__ s_src, const float* __restrict__ s_dst,
                       const int* __restrict__ src, const int* __restrict__ dst,
                       int* __restrict__ cursor, int2* __restrict__ epair, int E){
    int gt = blockIdx.x*256 + threadIdx.x;
    int e = gt >> 4, l4 = gt & 15;
    if (e >= E) return;
    float4 f  = *(const float4*)&ef[(size_t)e*EDIM + l4*4];
    float4 ae = *(const float4*)&A[2*FDIM + l4*4];
    float v = f.x*ae.x + f.y*ae.y + f.z*ae.z + f.w*ae.w;
    v += __shfl_xor(v, 8); v += __shfl_xor(v, 4);
    v += __shfl_xor(v, 2); v += __shfl_xor(v, 1);
    if (l4 == 0){
        int d = dst[e];
        float lg = v + s_src[src[e]] + s_dst[d];
        lg = lg > 0.f ? lg : LEAKY*lg;
        int p = atomicAdd(&cursor[d], 1);
        int2 pr; pr.x = src[e]; pr.y = __float_as_int(lg);
        epair[p] = pr;
    }
}

// final: 4 dst nodes per block, one wave per node; coalesced epair + shfl
__global__ __launch_bounds__(256) void k_out(const unsigned short* __restrict__ z16,
                                             const int* __restrict__ offsets,
                                             const int2* __restrict__ epair,
                                             float* __restrict__ out, int N){
    int n = blockIdx.x*4 + (threadIdx.x >> 6);
    int lane = threadIdx.x & 63;
    if (n >= N) return;
    int i0 = offsets[n], i1 = offsets[n+1];

    float mlane = -3.402823466e38f;
    for (int i = i0 + lane; i < i1; i += 64)
        mlane = fmaxf(mlane, __int_as_float(epair[i].y));
    float mx = mlane;
    #pragma unroll
    for (int o = 32; o > 0; o >>= 1)
        mx = fmaxf(mx, __shfl_xor(mx, o));

    float4 a[4];
    a[0] = make_float4(0,0,0,0); a[1] = a[0]; a[2] = a[0]; a[3] = a[0];
    float dw = 0.f;
    const unsigned short* zb = z16 + lane*4;

    for (int base = i0; base < i1; base += 64){
        int cnt = min(64, i1 - base);
        int2 pe = make_int2(0, 0);
        float w = 0.f;
        if (lane < cnt){
            pe = epair[base + lane];
            w = __expf(__int_as_float(pe.y) - mx);
        }
        dw += w;
        int j = 0;
        for (; j + 7 < cnt; j += 8){
            float wj[8]; int sj[8]; uint2 rj[8];
            #pragma unroll
            for (int q = 0; q < 8; ++q){
                wj[q] = __shfl(w, j + q);
                sj[q] = __shfl(pe.x, j + q);
            }
            #pragma unroll
            for (int q = 0; q < 8; ++q)
                rj[q] = *(const uint2*)&zb[(size_t)sj[q]*FDIM];
            #pragma unroll
            for (int q = 0; q < 8; ++q){
                a[q & 3].x += wj[q]*bf2f(rj[q].x & 0xffffu);
                a[q & 3].y += wj[q]*bf2f(rj[q].x >> 16);
                a[q & 3].z += wj[q]*bf2f(rj[q].y & 0xffffu);
                a[q & 3].w += wj[q]*bf2f(rj[q].y >> 16);
            }
        }
        for (; j < cnt; ++j){
            float wq = __shfl(w, j);
            int   sq = __shfl(pe.x, j);
            uint2 r0 = *(const uint2*)&zb[(size_t)sq*FDIM];
            a[0].x += wq*bf2f(r0.x & 0xffffu);
            a[0].y += wq*bf2f(r0.x >> 16);
            a[0].z += wq*bf2f(r0.y & 0xffffu);
            a[0].w += wq*bf2f(r0.y >> 16);
        }
    }

    #pragma unroll
    for (int o = 32; o > 0; o >>= 1)
        dw += __shfl_xor(dw, o);

    float inv = (i1 > i0) ? 1.f / dw : 0.f;
    float4 res;
    res.x = ((a[0].x + a[1].x) + (a[2].x + a[3].x)) * inv;
    res.y = ((a[0].y + a[1].y) + (a[2].y + a[3].y)) * inv;
    res.z = ((a[0].z + a[1].z) + (a[2].z + a[3].z)) * inv;
    res.w = ((a[0].w + a[1].w) + (a[2].w + a[3].w)) * inv;
    *(float4*)&out[(size_t)n*FDIM + lane*4] = res;
}

extern "C" void kernel_launch(void* const* d_in, const int* in_sizes, int n_in,
                              void* d_out, int out_size, void* d_ws, size_t ws_size,
                              hipStream_t stream){
    const float* h  = (const float*)d_in[0];
    const float* ef = (const float*)d_in[1];
    const float* W  = (const float*)d_in[2];
    const float* A  = (const float*)d_in[3];
    const int*  src = (const int*)d_in[4];
    const int*  dst = (const int*)d_in[5];
    float* out = (float*)d_out;
    int N = in_sizes[0] / FDIM;
    int E = in_sizes[4];

    char* ws = (char*)d_ws;
    size_t off = 0;
    auto alloc = [&](size_t nbytes)->char*{
        char* p = ws + off;
        off = (off + nbytes + 255) & ~(size_t)255;
        return p;
    };
    unsigned short* z16 = (unsigned short*)alloc((size_t)N*FDIM*2);
    unsigned short* W16 = (unsigned short*)alloc((size_t)FDIM*FDIM*2);
    float* s_src  = (float*)alloc((size_t)N*4);
    float* s_dst  = (float*)alloc((size_t)N*4);
    int*   counts = (int*)alloc((size_t)(N+1)*4);
    int*   cursor = (int*)alloc((size_t)N*4);
    int2*  epair  = (int2*)alloc((size_t)E*8);
    int*   bsums  = (int*)alloc(1024*4);

    int nb = (N + 1023)/1024;

    hipMemsetAsync(counts, 0, (size_t)(N+1)*4, stream);
    hipLaunchKernelGGL(k_wconv, dim3(64), dim3(256), 0, stream, W, W16);
    hipLaunchKernelGGL(k_gemm, dim3((N+BM-1)/BM), dim3(256), 0, stream,
                       h, W16, A, z16, s_src, s_dst, N);
    hipLaunchKernelGGL(k_count, dim3((E+255)/256), dim3(256), 0, stream,
                       dst, counts, E);
    hipLaunchKernelGGL(k_chunk_sums, dim3(nb), dim3(256), 0, stream,
                       counts, bsums, N);
    hipLaunchKernelGGL(k_scan_small, dim3(1), dim3(1024), 0, stream,
                       bsums, nb);
    hipLaunchKernelGGL(k_scan_chunks, dim3(nb), dim3(256), 0, stream,
                       counts, cursor, bsums, N, E);
    hipLaunchKernelGGL(k_edge, dim3((E+15)/16), dim3(256), 0, stream,
                       ef, A, s_src, s_dst, src, dst, cursor, epair, E);
    hipLaunchKernelGGL(k_out, dim3((N+3)/4), dim3(256), 0, stream,
                       z16, counts, epair, out, N);
}